// Round 2
// baseline (537.981 us; speedup 1.0000x reference)
//
#include <hip/hip_runtime.h>
#include <stdint.h>

#define B_ 16
#define C_ 512
#define N_ 4096
#define K_ 64
#define NUM_STAGES 3

typedef __bf16 bf16x8 __attribute__((ext_vector_type(8)));
typedef float f32x4 __attribute__((ext_vector_type(4)));

__device__ __forceinline__ uint16_t f2bf(float x) {
  union { float f; uint32_t u; } v; v.f = x;
  uint32_t r = (v.u + 0x7FFFu + ((v.u >> 16) & 1u)) >> 16;
  return (uint16_t)r;
}

__device__ __forceinline__ void async16(const uint16_t* g, uint16_t* l) {
  __builtin_amdgcn_global_load_lds(
      (const __attribute__((address_space(1))) unsigned int*)g,
      (__attribute__((address_space(3))) unsigned int*)l, 16, 0, 0);
}

// ---------------- prep: fp32 feats -> bf16 f [B][C][N] and fT [B][N][C] ----
// (round-0 exact: measured ~79us, 0 bank conflicts, occupancy 66%)
__global__ __launch_bounds__(256) void k_prep(const float* __restrict__ feats,
                                              uint16_t* __restrict__ f16,
                                              uint16_t* __restrict__ fT16) {
  __shared__ uint16_t tile[64][65];
  int b = blockIdx.z, c0 = blockIdx.y * 64, n0 = blockIdx.x * 64;
  int t = threadIdx.x;
  const float* src = feats + ((size_t)b * C_ + c0) * N_ + n0;
  uint16_t* dst = f16 + ((size_t)b * C_ + c0) * N_ + n0;
  int cl = t >> 4;          // 0..15
  int nl = (t & 15) * 4;    // 0..60
#pragma unroll
  for (int i = 0; i < 4; ++i) {
    int c = cl + 16 * i;
    float4 v = *(const float4*)(src + (size_t)c * N_ + nl);
    ushort4 x;
    x.x = f2bf(v.x); x.y = f2bf(v.y); x.z = f2bf(v.z); x.w = f2bf(v.w);
    *(ushort4*)(dst + (size_t)c * N_ + nl) = x;
    tile[c][nl + 0] = x.x; tile[c][nl + 1] = x.y;
    tile[c][nl + 2] = x.z; tile[c][nl + 3] = x.w;
  }
  __syncthreads();
  uint16_t* dstT = fT16 + ((size_t)b * N_ + n0) * C_ + c0;
#pragma unroll
  for (int i = 0; i < 4; ++i) {
    int n = cl + 16 * i;
    int c = nl;
    ushort4 y;
    y.x = tile[c + 0][n]; y.y = tile[c + 1][n];
    y.z = tile[c + 2][n]; y.w = tile[c + 3][n];
    *(ushort4*)(dstT + (size_t)n * C_ + c) = y;
  }
}

// ---------------- init: l2norm(bases over C) -> basis [B][C][K], basisT [B][K][C]
__global__ __launch_bounds__(256) void k_init_basis(const float* __restrict__ bases,
                                                    uint16_t* __restrict__ basis,
                                                    uint16_t* __restrict__ basisT) {
  int b = blockIdx.x;
  int t = threadIdx.x;
  __shared__ float red[256];
  __shared__ float inv[64];
  int k = t & 63;
  float s = 0.f;
  for (int c = (t >> 6); c < C_; c += 4) {
    float v = bases[c * K_ + k];
    s += v * v;
  }
  red[t] = s;
  __syncthreads();
  if (t < 64) {
    float tot = red[t] + red[t + 64] + red[t + 128] + red[t + 192];
    inv[t] = 1.f / (1e-6f + sqrtf(tot));
  }
  __syncthreads();
  uint16_t* ob = basis + (size_t)b * C_ * K_;
  for (int i = 0; i < (C_ * K_) / 256; ++i) {
    int idx = t + 256 * i;
    int kk = idx & 63;
    ob[idx] = f2bf(bases[idx] * inv[kk]);
  }
  uint16_t* obT = basisT + (size_t)b * K_ * C_;
  for (int i = 0; i < (C_ * K_) / 256; ++i) {
    int idx = t + 256 * i;
    int kk = idx >> 9;
    int cc = idx & 511;
    obT[idx] = f2bf(bases[cc * K_ + kk] * inv[kk]);
  }
}

// ---------------- GEMM1 + fused softmax, v3:
// whole basisT[b] (64x512 = 64KB) resident in LDS (staged ONCE, XOR-swizzled);
// A-fragments loaded global->VGPR directly (dwordx4, 16 rows x 64B segments);
// ZERO barriers in the K-loop. 512 threads, n-tile 128, grid 32x16 = 2 blocks/CU.
__global__ __launch_bounds__(512, 4) void k_gemm1(const uint16_t* __restrict__ fT,
                                                  const uint16_t* __restrict__ basisT,
                                                  uint16_t* __restrict__ attn,   // [B][N][K]
                                                  uint16_t* __restrict__ attnT,  // [B][K][N]
                                                  int write_attn) {
  __shared__ __attribute__((aligned(16))) uint16_t ldsB[K_ * C_];  // 64 KB
  int b = blockIdx.y;
  int n0 = blockIdx.x * 128;
  int t = threadIdx.x;
  int w = t >> 6, lane = t & 63, l15 = lane & 15, quad = lane >> 4;
  const uint16_t* Bm = basisT + (size_t)b * K_ * C_;
  // stage: LDS row rb (64 x 16B slots), slot v holds global chunk m = v ^ (rb&7)
#pragma unroll
  for (int r = 0; r < 8; ++r) {
    int o = r * 512 + t;        // linear 16B-slot index; one wave = one full row
    int rb = o >> 6;
    int v = o & 63;
    int m = v ^ (rb & 7);
    async16(Bm + (size_t)rb * C_ + m * 8, ldsB + (r * 512 + (t & 448)) * 8);
  }
  const uint16_t* A = fT + ((size_t)b * N_ + n0 + 16 * w + l15) * C_;
  f32x4 acc[4] = {};
  __syncthreads();  // drain staging; the ONLY barrier before epilogue
#pragma unroll
  for (int it = 0; it < 8; ++it) {
#pragma unroll
    for (int s = 0; s < 2; ++s) {
      int m = it * 8 + s * 4 + quad;                      // global c-chunk
      bf16x8 af = *(const bf16x8*)(A + m * 8);
#pragma unroll
      for (int t4 = 0; t4 < 4; ++t4) {
        int rb = 16 * t4 + l15;
        bf16x8 bv = *(const bf16x8*)(ldsB + ((size_t)rb * 64 + (m ^ (rb & 7))) * 8);
        acc[t4] = __builtin_amdgcn_mfma_f32_16x16x32_bf16(af, bv, acc[t4], 0, 0, 0);
      }
    }
  }
  float p[4][4];
#pragma unroll
  for (int r = 0; r < 4; ++r) {
    float m = fmaxf(fmaxf(acc[0][r], acc[1][r]), fmaxf(acc[2][r], acc[3][r]));
    m = fmaxf(m, __shfl_xor(m, 1));
    m = fmaxf(m, __shfl_xor(m, 2));
    m = fmaxf(m, __shfl_xor(m, 4));
    m = fmaxf(m, __shfl_xor(m, 8));
    float s = 0.f;
#pragma unroll
    for (int t4 = 0; t4 < 4; ++t4) { p[t4][r] = __expf(acc[t4][r] - m); s += p[t4][r]; }
    s += __shfl_xor(s, 1); s += __shfl_xor(s, 2);
    s += __shfl_xor(s, 4); s += __shfl_xor(s, 8);
    float inv = 1.f / s;
#pragma unroll
    for (int t4 = 0; t4 < 4; ++t4) p[t4][r] *= inv;
  }
  if (write_attn) {
    uint16_t* oa = attn + ((size_t)b * N_ + n0 + 16 * w + quad * 4) * K_;
#pragma unroll
    for (int r = 0; r < 4; ++r) {
#pragma unroll
      for (int t4 = 0; t4 < 4; ++t4) oa[(size_t)r * K_ + 16 * t4 + l15] = f2bf(p[t4][r]);
    }
  }
#pragma unroll
  for (int t4 = 0; t4 < 4; ++t4) {
    ushort4 y;
    y.x = f2bf(p[t4][0]); y.y = f2bf(p[t4][1]);
    y.z = f2bf(p[t4][2]); y.w = f2bf(p[t4][3]);
    *(ushort4*)(attnT + ((size_t)b * K_ + 16 * t4 + l15) * N_ + n0 + 16 * w + quad * 4) = y;
  }
}

// ---------------- GEMM2, v3: pure streaming, NO LDS, NO barriers.
// A (f16 rows, block-exclusive) and B (attnT, L2/L3-resident) global->VGPR.
__global__ __launch_bounds__(256, 4) void k_gemm2(const uint16_t* __restrict__ f16,
                                                  const uint16_t* __restrict__ attnT,
                                                  float* __restrict__ brawT) {
  int b = blockIdx.z;
  int c0 = blockIdx.x * 32;
  int slice = blockIdx.y;
  int ns0 = slice * 1024;
  int t = threadIdx.x, w = t >> 6, lane = t & 63, l15 = lane & 15, quad = lane >> 4;
  int h = w >> 1, kh = w & 1;
  const uint16_t* A = f16 + ((size_t)b * C_ + c0 + 16 * h + l15) * N_;
  const uint16_t* Bm = attnT + ((size_t)b * K_ + 32 * kh) * N_;
  f32x4 acc[2] = {};
#pragma unroll 4
  for (int it = 0; it < 16; ++it) {
#pragma unroll
    for (int s = 0; s < 2; ++s) {
      int n = ns0 + it * 64 + (s * 4 + quad) * 8;
      bf16x8 af = *(const bf16x8*)(A + n);
#pragma unroll
      for (int t2 = 0; t2 < 2; ++t2) {
        bf16x8 bv = *(const bf16x8*)(Bm + (size_t)(16 * t2 + l15) * N_ + n);
        acc[t2] = __builtin_amdgcn_mfma_f32_16x16x32_bf16(af, bv, acc[t2], 0, 0, 0);
      }
    }
  }
  float* out = brawT + ((size_t)slice * B_ + b) * K_ * C_;
#pragma unroll
  for (int t2 = 0; t2 < 2; ++t2) {
    int k = 32 * kh + 16 * t2 + l15;
    float4 v = make_float4(acc[t2][0], acc[t2][1], acc[t2][2], acc[t2][3]);
    *(float4*)(out + (size_t)k * C_ + c0 + 16 * h + quad * 4) = v;
  }
}

// ---------------- FUSED l2norm + transpose (unchanged)
__global__ __launch_bounds__(256) void k_l2fused(const float* __restrict__ brawT,
                                                 uint16_t* __restrict__ basisT,
                                                 uint16_t* __restrict__ basis) {
  __shared__ float red[4][128];
  __shared__ float invs[4];
  int b = blockIdx.x, kg = blockIdx.y;
  int t = threadIdx.x;
  int c4 = (t & 127) * 4;
  int khalf = t >> 7;
  float4 bs[2];
  float pr[2];
#pragma unroll
  for (int i = 0; i < 2; ++i) {
    int k = kg * 4 + khalf * 2 + i;
    float4 a = make_float4(0.f, 0.f, 0.f, 0.f);
#pragma unroll
    for (int s = 0; s < 4; ++s) {
      const float* rp = brawT + (((size_t)s * B_ + b) * K_ + k) * C_ + c4;
      float4 v = *(const float4*)rp;
      a.x += v.x; a.y += v.y; a.z += v.z; a.w += v.w;
    }
    bs[i] = a;
    pr[i] = a.x * a.x + a.y * a.y + a.z * a.z + a.w * a.w;
  }
  red[khalf * 2 + 0][t & 127] = pr[0];
  red[khalf * 2 + 1][t & 127] = pr[1];
  __syncthreads();
  if (t < 4) {
    float s = 0.f;
#pragma unroll
    for (int j = 0; j < 128; ++j) s += red[t][j];
    invs[t] = 1.f / (1e-6f + sqrtf(s));
  }
  __syncthreads();
#pragma unroll
  for (int i = 0; i < 2; ++i) {
    int kk = khalf * 2 + i;
    int k = kg * 4 + kk;
    float inv = invs[kk];
    ushort4 y;
    y.x = f2bf(bs[i].x * inv); y.y = f2bf(bs[i].y * inv);
    y.z = f2bf(bs[i].z * inv); y.w = f2bf(bs[i].w * inv);
    *(ushort4*)(basisT + ((size_t)b * K_ + k) * C_ + c4) = y;
    uint16_t* ob = basis + (size_t)b * C_ * K_ + k;
    ob[(size_t)(c4 + 0) * K_] = y.x;
    ob[(size_t)(c4 + 1) * K_] = y.y;
    ob[(size_t)(c4 + 2) * K_] = y.z;
    ob[(size_t)(c4 + 3) * K_] = y.w;
  }
}

// ---------------- recon v2: register-direct MFMA operands (K=64, one step),
// LDS used only for the fp32 output transpose.
__global__ __launch_bounds__(256) void k_recon(const uint16_t* __restrict__ attn,
                                               const uint16_t* __restrict__ basis,
                                               float* __restrict__ out) {
  __shared__ __attribute__((aligned(16))) float ldsT[64 * 68];  // 17.4 KB
  int b = blockIdx.z, c0 = blockIdx.y * 64, n0 = blockIdx.x * 64;
  int t = threadIdx.x, w = t >> 6, lane = t & 63, l15 = lane & 15, quad = lane >> 4;
  const uint16_t* A = attn + ((size_t)b * N_ + n0 + 16 * w + l15) * K_;
  const uint16_t* Bm = basis + ((size_t)b * C_ + c0) * K_;
  f32x4 acc[4] = {};
#pragma unroll
  for (int s = 0; s < 2; ++s) {
    int cc = (s * 4 + quad) * 8;
    bf16x8 af = *(const bf16x8*)(A + cc);
#pragma unroll
    for (int t4 = 0; t4 < 4; ++t4) {
      bf16x8 bv = *(const bf16x8*)(Bm + (size_t)(16 * t4 + l15) * K_ + cc);
      acc[t4] = __builtin_amdgcn_mfma_f32_16x16x32_bf16(af, bv, acc[t4], 0, 0, 0);
    }
  }
  // transpose through LDS: acc holds D[n'][c'] with n'=16w+quad*4+r, c'=16t4+l15
#pragma unroll
  for (int t4 = 0; t4 < 4; ++t4) {
    float4 v = make_float4(acc[t4][0], acc[t4][1], acc[t4][2], acc[t4][3]);
    *(float4*)(ldsT + (size_t)(16 * t4 + l15) * 68 + 16 * w + quad * 4) = v;
  }
  __syncthreads();
  float* op = out + ((size_t)b * C_ + c0) * N_ + n0;
#pragma unroll
  for (int j = 0; j < 16; ++j) {
    int c = 4 * j + w;
    op[(size_t)c * N_ + lane] = ldsT[(size_t)c * 68 + lane];  // 256B/row
  }
}

extern "C" void kernel_launch(void* const* d_in, const int* in_sizes, int n_in,
                              void* d_out, int out_size, void* d_ws, size_t ws_size,
                              hipStream_t stream) {
  const float* feats = (const float*)d_in[0];
  const float* bases = (const float*)d_in[1];
  float* out = (float*)d_out;
  char* ws = (char*)d_ws;
  uint16_t* f16 = (uint16_t*)(ws);                         // 64 MB
  uint16_t* fT16 = (uint16_t*)(ws + 67108864);             // 64 MB
  uint16_t* attn = (uint16_t*)(ws + 134217728);            // 8 MB
  uint16_t* attnT = (uint16_t*)(ws + 142606336);           // 8 MB
  uint16_t* basis = (uint16_t*)(ws + 150994944);           // 1 MB
  uint16_t* basisT = (uint16_t*)(ws + 152043520);          // 1 MB
  float* brawT = (float*)(ws + 153092096);                 // 8 MB (4 slices)

  k_prep<<<dim3(64, 8, 16), 256, 0, stream>>>(feats, f16, fT16);
  k_init_basis<<<16, 256, 0, stream>>>(bases, basis, basisT);
  for (int st = 0; st < NUM_STAGES; ++st) {
    k_gemm1<<<dim3(32, 16), 512, 0, stream>>>(fT16, basisT, attn, attnT,
                                              st == NUM_STAGES - 1 ? 1 : 0);
    k_gemm2<<<dim3(16, 4, 16), 256, 0, stream>>>(f16, attnT, brawT);
    k_l2fused<<<dim3(16, 16), 256, 0, stream>>>(brawT, basisT, basis);
  }
  k_recon<<<dim3(64, 8, 16), 256, 0, stream>>>(attn, basis, out);
}

// Round 3
// 460.538 us; speedup vs baseline: 1.1682x; 1.1682x over previous
//
#include <hip/hip_runtime.h>
#include <stdint.h>

#define B_ 16
#define C_ 512
#define N_ 4096
#define K_ 64
#define NUM_STAGES 3

typedef __bf16 bf16x8 __attribute__((ext_vector_type(8)));
typedef float f32x4 __attribute__((ext_vector_type(4)));

__device__ __forceinline__ uint16_t f2bf(float x) {
  union { float f; uint32_t u; } v; v.f = x;
  uint32_t r = (v.u + 0x7FFFu + ((v.u >> 16) & 1u)) >> 16;
  return (uint16_t)r;
}

__device__ __forceinline__ void async16(const uint16_t* g, uint16_t* l) {
  __builtin_amdgcn_global_load_lds(
      (const __attribute__((address_space(1))) unsigned int*)g,
      (__attribute__((address_space(3))) unsigned int*)l, 16, 0, 0);
}

// ---------------- prep: fp32 feats -> bf16 f [B][C][N] and fT [B][N][C] ----
// (round-0 exact: 79us, 0 bank conflicts)
__global__ __launch_bounds__(256) void k_prep(const float* __restrict__ feats,
                                              uint16_t* __restrict__ f16,
                                              uint16_t* __restrict__ fT16) {
  __shared__ uint16_t tile[64][65];
  int b = blockIdx.z, c0 = blockIdx.y * 64, n0 = blockIdx.x * 64;
  int t = threadIdx.x;
  const float* src = feats + ((size_t)b * C_ + c0) * N_ + n0;
  uint16_t* dst = f16 + ((size_t)b * C_ + c0) * N_ + n0;
  int cl = t >> 4;          // 0..15
  int nl = (t & 15) * 4;    // 0..60
#pragma unroll
  for (int i = 0; i < 4; ++i) {
    int c = cl + 16 * i;
    float4 v = *(const float4*)(src + (size_t)c * N_ + nl);
    ushort4 x;
    x.x = f2bf(v.x); x.y = f2bf(v.y); x.z = f2bf(v.z); x.w = f2bf(v.w);
    *(ushort4*)(dst + (size_t)c * N_ + nl) = x;
    tile[c][nl + 0] = x.x; tile[c][nl + 1] = x.y;
    tile[c][nl + 2] = x.z; tile[c][nl + 3] = x.w;
  }
  __syncthreads();
  uint16_t* dstT = fT16 + ((size_t)b * N_ + n0) * C_ + c0;
#pragma unroll
  for (int i = 0; i < 4; ++i) {
    int n = cl + 16 * i;
    int c = nl;
    ushort4 y;
    y.x = tile[c + 0][n]; y.y = tile[c + 1][n];
    y.z = tile[c + 2][n]; y.w = tile[c + 3][n];
    *(ushort4*)(dstT + (size_t)n * C_ + c) = y;
  }
}

// ---------------- init: l2norm(bases over C) -> basis [B][C][K], basisT [B][K][C]
__global__ __launch_bounds__(256) void k_init_basis(const float* __restrict__ bases,
                                                    uint16_t* __restrict__ basis,
                                                    uint16_t* __restrict__ basisT) {
  int b = blockIdx.x;
  int t = threadIdx.x;
  __shared__ float red[256];
  __shared__ float inv[64];
  int k = t & 63;
  float s = 0.f;
  for (int c = (t >> 6); c < C_; c += 4) {
    float v = bases[c * K_ + k];
    s += v * v;
  }
  red[t] = s;
  __syncthreads();
  if (t < 64) {
    float tot = red[t] + red[t + 64] + red[t + 128] + red[t + 192];
    inv[t] = 1.f / (1e-6f + sqrtf(tot));
  }
  __syncthreads();
  uint16_t* ob = basis + (size_t)b * C_ * K_;
  for (int i = 0; i < (C_ * K_) / 256; ++i) {
    int idx = t + 256 * i;
    int kk = idx & 63;
    ob[idx] = f2bf(bases[idx] * inv[kk]);
  }
  uint16_t* obT = basisT + (size_t)b * K_ * C_;
  for (int i = 0; i < (C_ * K_) / 256; ++i) {
    int idx = t + 256 * i;
    int kk = idx >> 9;
    int cc = idx & 511;
    obT[idx] = f2bf(bases[cc * K_ + kk] * inv[kk]);
  }
}

// ---------------- GEMM1 + fused softmax (round-0 exact config)
__global__ __launch_bounds__(256) void k_gemm1(const uint16_t* __restrict__ fT,
                                               const uint16_t* __restrict__ basisT,
                                               uint16_t* __restrict__ attn,    // [B][N][K]
                                               uint16_t* __restrict__ attnT,   // [B][K][N]
                                               int write_attn) {
  __shared__ __attribute__((aligned(16))) uint16_t ldsA[64 * 64];
  __shared__ __attribute__((aligned(16))) uint16_t ldsB[64 * 64];
  int b = blockIdx.y;
  int n0 = blockIdx.x * 64;
  int t = threadIdx.x;
  int w = t >> 6, lane = t & 63, l15 = lane & 15, quad = lane >> 4;
  const uint16_t* A = fT + ((size_t)b * N_ + n0) * C_;
  const uint16_t* Bm = basisT + (size_t)b * K_ * C_;
  f32x4 acc[4] = {};
  for (int cs = 0; cs < C_; cs += 64) {
    __syncthreads();
#pragma unroll
    for (int r = 0; r < 2; ++r) {
      int e = r * 256 + t;
      int row = e >> 3, ch = e & 7;
      int sch = (ch + row) & 7;
      async16(A + (size_t)row * C_ + cs + sch * 8, ldsA + (r * 256 + (t & 192)) * 8);
    }
#pragma unroll
    for (int r = 0; r < 2; ++r) {
      int e = r * 256 + t;
      int row = e >> 3, ch = e & 7;
      int sch = (ch + row) & 7;
      async16(Bm + (size_t)row * C_ + cs + sch * 8, ldsB + (r * 256 + (t & 192)) * 8);
    }
    __syncthreads();
#pragma unroll
    for (int s = 0; s < 2; ++s) {
      int cc = s * 4 + quad;
      int ra = 16 * w + l15;
      bf16x8 af = *(const bf16x8*)(ldsA + (ra * 8 + ((cc - ra) & 7)) * 8);
#pragma unroll
      for (int t4 = 0; t4 < 4; ++t4) {
        int rb = 16 * t4 + l15;
        bf16x8 bv = *(const bf16x8*)(ldsB + (rb * 8 + ((cc - rb) & 7)) * 8);
        acc[t4] = __builtin_amdgcn_mfma_f32_16x16x32_bf16(af, bv, acc[t4], 0, 0, 0);
      }
    }
  }
  float p[4][4];
#pragma unroll
  for (int r = 0; r < 4; ++r) {
    float m = fmaxf(fmaxf(acc[0][r], acc[1][r]), fmaxf(acc[2][r], acc[3][r]));
    m = fmaxf(m, __shfl_xor(m, 1));
    m = fmaxf(m, __shfl_xor(m, 2));
    m = fmaxf(m, __shfl_xor(m, 4));
    m = fmaxf(m, __shfl_xor(m, 8));
    float s = 0.f;
#pragma unroll
    for (int t4 = 0; t4 < 4; ++t4) { p[t4][r] = __expf(acc[t4][r] - m); s += p[t4][r]; }
    s += __shfl_xor(s, 1); s += __shfl_xor(s, 2);
    s += __shfl_xor(s, 4); s += __shfl_xor(s, 8);
    float inv = 1.f / s;
#pragma unroll
    for (int t4 = 0; t4 < 4; ++t4) p[t4][r] *= inv;
  }
  if (write_attn) {
    uint16_t* oa = attn + ((size_t)b * N_ + n0 + 16 * w + quad * 4) * K_;
#pragma unroll
    for (int r = 0; r < 4; ++r) {
#pragma unroll
      for (int t4 = 0; t4 < 4; ++t4) oa[(size_t)r * K_ + 16 * t4 + l15] = f2bf(p[t4][r]);
    }
  }
#pragma unroll
  for (int t4 = 0; t4 < 4; ++t4) {
    ushort4 y;
    y.x = f2bf(p[t4][0]); y.y = f2bf(p[t4][1]);
    y.z = f2bf(p[t4][2]); y.w = f2bf(p[t4][3]);
    *(ushort4*)(attnT + ((size_t)b * K_ + 16 * t4 + l15) * N_ + n0 + 16 * w + quad * 4) = y;
  }
}

// ---------------- GEMM2 (round-0 structure): brawT[s][b][k][c], runtime split-K
// v4 change: slice_n is a parameter so the host can run split-8 (32 waves/CU)
__global__ __launch_bounds__(256) void k_gemm2(const uint16_t* __restrict__ f16,
                                               const uint16_t* __restrict__ attnT,
                                               float* __restrict__ brawT,
                                               int slice_n) {
  __shared__ __attribute__((aligned(16))) uint16_t ldsA[32 * 64];
  __shared__ __attribute__((aligned(16))) uint16_t ldsB[64 * 64];
  int b = blockIdx.z;
  int c0 = blockIdx.x * 32;
  int slice = blockIdx.y;
  int ns0 = slice * slice_n;
  int t = threadIdx.x, w = t >> 6, lane = t & 63, l15 = lane & 15, quad = lane >> 4;
  int h = w >> 1, kh = w & 1;
  const uint16_t* A = f16 + ((size_t)b * C_ + c0) * N_;
  const uint16_t* Bm = attnT + (size_t)b * K_ * N_;
  f32x4 acc[2] = {};
  for (int ns = ns0; ns < ns0 + slice_n; ns += 64) {
    __syncthreads();
    {
      int row = t >> 3, ch = t & 7;
      int sch = (ch + row) & 7;
      async16(A + (size_t)row * N_ + ns + sch * 8, ldsA + (t & 192) * 8);
    }
#pragma unroll
    for (int r = 0; r < 2; ++r) {
      int e = r * 256 + t;
      int row = e >> 3, ch = e & 7;
      int sch = (ch + row) & 7;
      async16(Bm + (size_t)row * N_ + ns + sch * 8, ldsB + (r * 256 + (t & 192)) * 8);
    }
    __syncthreads();
#pragma unroll
    for (int s = 0; s < 2; ++s) {
      int cc = s * 4 + quad;
      int ra = 16 * h + l15;
      bf16x8 af = *(const bf16x8*)(ldsA + (ra * 8 + ((cc - ra) & 7)) * 8);
#pragma unroll
      for (int t2 = 0; t2 < 2; ++t2) {
        int rb = 32 * kh + 16 * t2 + l15;
        bf16x8 bv = *(const bf16x8*)(ldsB + (rb * 8 + ((cc - rb) & 7)) * 8);
        acc[t2] = __builtin_amdgcn_mfma_f32_16x16x32_bf16(af, bv, acc[t2], 0, 0, 0);
      }
    }
  }
  float* out = brawT + ((size_t)slice * B_ + b) * K_ * C_;
#pragma unroll
  for (int t2 = 0; t2 < 2; ++t2) {
    int k = 32 * kh + 16 * t2 + l15;
    float4 v = make_float4(acc[t2][0], acc[t2][1], acc[t2][2], acc[t2][3]);
    *(float4*)(out + (size_t)k * C_ + c0 + 16 * h + quad * 4) = v;
  }
}

// ---------------- FUSED l2norm + transpose: runtime slice count
__global__ __launch_bounds__(256) void k_l2fused(const float* __restrict__ brawT,
                                                 uint16_t* __restrict__ basisT,
                                                 uint16_t* __restrict__ basis,
                                                 int nsl) {
  __shared__ float red[4][128];
  __shared__ float invs[4];
  int b = blockIdx.x, kg = blockIdx.y;
  int t = threadIdx.x;
  int c4 = (t & 127) * 4;       // c chunk of 4
  int khalf = t >> 7;           // 0/1 -> k' = khalf*2 + i
  float4 bs[2];
  float pr[2];
#pragma unroll
  for (int i = 0; i < 2; ++i) {
    int k = kg * 4 + khalf * 2 + i;
    float4 a = make_float4(0.f, 0.f, 0.f, 0.f);
    for (int s = 0; s < nsl; ++s) {
      const float* rp = brawT + (((size_t)s * B_ + b) * K_ + k) * C_ + c4;
      float4 v = *(const float4*)rp;
      a.x += v.x; a.y += v.y; a.z += v.z; a.w += v.w;
    }
    bs[i] = a;
    pr[i] = a.x * a.x + a.y * a.y + a.z * a.z + a.w * a.w;
  }
  red[khalf * 2 + 0][t & 127] = pr[0];
  red[khalf * 2 + 1][t & 127] = pr[1];
  __syncthreads();
  if (t < 4) {
    float s = 0.f;
#pragma unroll
    for (int j = 0; j < 128; ++j) s += red[t][j];
    invs[t] = 1.f / (1e-6f + sqrtf(s));
  }
  __syncthreads();
#pragma unroll
  for (int i = 0; i < 2; ++i) {
    int kk = khalf * 2 + i;
    int k = kg * 4 + kk;
    float inv = invs[kk];
    ushort4 y;
    y.x = f2bf(bs[i].x * inv); y.y = f2bf(bs[i].y * inv);
    y.z = f2bf(bs[i].z * inv); y.w = f2bf(bs[i].w * inv);
    *(ushort4*)(basisT + ((size_t)b * K_ + k) * C_ + c4) = y;
    uint16_t* ob = basis + (size_t)b * C_ * K_ + k;
    ob[(size_t)(c4 + 0) * K_] = y.x;
    ob[(size_t)(c4 + 1) * K_] = y.y;
    ob[(size_t)(c4 + 2) * K_] = y.z;
    ob[(size_t)(c4 + 3) * K_] = y.w;
  }
}

// ---------------- recon: out[b,c,n] = sum_k basis[c,k]*attn[n,k] (fp32)
// round-0 tile; v4 epilogue: float4 stores (4 rows x 256B = 1KB per wave-instr)
__global__ __launch_bounds__(256) void k_recon(const uint16_t* __restrict__ attn,
                                               const uint16_t* __restrict__ basis,
                                               float* __restrict__ out) {
  __shared__ __attribute__((aligned(16))) char smem[64 * 68 * 4]; // 17.4 KB union
  uint16_t* ldsA = (uint16_t*)smem;              // 64 n x 64 k (8 KB)
  uint16_t* ldsB = (uint16_t*)(smem + 8192);     // 64 c x 64 k (8 KB)
  float* ldsT = (float*)smem;                    // 64 c x 68 n
  int b = blockIdx.z, c0 = blockIdx.y * 64, n0 = blockIdx.x * 64;
  int t = threadIdx.x, w = t >> 6, lane = t & 63, l15 = lane & 15, quad = lane >> 4;
  const uint16_t* A = attn + ((size_t)b * N_ + n0) * K_;
  const uint16_t* Bm = basis + ((size_t)b * C_ + c0) * K_;
#pragma unroll
  for (int r = 0; r < 2; ++r) {
    int e = r * 256 + t;
    int row = e >> 3, ch = e & 7, sch = (ch + row) & 7;
    async16(A + (size_t)row * K_ + sch * 8, ldsA + (r * 256 + (t & 192)) * 8);
  }
#pragma unroll
  for (int r = 0; r < 2; ++r) {
    int e = r * 256 + t;
    int row = e >> 3, ch = e & 7, sch = (ch + row) & 7;
    async16(Bm + (size_t)row * K_ + sch * 8, ldsB + (r * 256 + (t & 192)) * 8);
  }
  f32x4 acc[4] = {};
  __syncthreads();
#pragma unroll
  for (int s = 0; s < 2; ++s) {
    int cc = s * 4 + quad;
    int ra = 16 * w + l15;
    bf16x8 af = *(const bf16x8*)(ldsA + (ra * 8 + ((cc - ra) & 7)) * 8);
#pragma unroll
    for (int t4 = 0; t4 < 4; ++t4) {
      int rb = 16 * t4 + l15;
      bf16x8 bv = *(const bf16x8*)(ldsB + (rb * 8 + ((cc - rb) & 7)) * 8);
      acc[t4] = __builtin_amdgcn_mfma_f32_16x16x32_bf16(af, bv, acc[t4], 0, 0, 0);
    }
  }
  // transpose through LDS: acc holds D[n'][c'] with n'=16w+quad*4+r, c'=16t4+l15
  __syncthreads();
#pragma unroll
  for (int t4 = 0; t4 < 4; ++t4) {
    float4 v = make_float4(acc[t4][0], acc[t4][1], acc[t4][2], acc[t4][3]);
    *(float4*)(ldsT + (size_t)(16 * t4 + l15) * 68 + 16 * w + quad * 4) = v;
  }
  __syncthreads();
  float* op = out + ((size_t)b * C_ + c0) * N_ + n0;
  int n4 = l15 * 4;
#pragma unroll
  for (int j = 0; j < 4; ++j) {
    int c = 16 * j + 4 * w + quad;   // wave covers 4 rows x 256B = 1KB per instr
    *(float4*)(op + (size_t)c * N_ + n4) = *(const float4*)(ldsT + (size_t)c * 68 + n4);
  }
}

extern "C" void kernel_launch(void* const* d_in, const int* in_sizes, int n_in,
                              void* d_out, int out_size, void* d_ws, size_t ws_size,
                              hipStream_t stream) {
  const float* feats = (const float*)d_in[0];
  const float* bases = (const float*)d_in[1];
  float* out = (float*)d_out;
  char* ws = (char*)d_ws;
  uint16_t* f16 = (uint16_t*)(ws);                         // 64 MB
  uint16_t* fT16 = (uint16_t*)(ws + 67108864);             // 64 MB
  uint16_t* attn = (uint16_t*)(ws + 134217728);            // 8 MB
  uint16_t* attnT = (uint16_t*)(ws + 142606336);           // 8 MB
  uint16_t* basis = (uint16_t*)(ws + 150994944);           // 1 MB
  uint16_t* basisT = (uint16_t*)(ws + 152043520);          // 1 MB
  float* brawT = (float*)(ws + 153092096);                 // up to 16 MB (8 slices)

  // split-8 needs brawT end = 153092096 + 8*16*64*512*4 = 169869312 bytes
  int nsl = (ws_size >= (size_t)169869312) ? 8 : 4;
  int slice_n = N_ / nsl;

  k_prep<<<dim3(64, 8, 16), 256, 0, stream>>>(feats, f16, fT16);
  k_init_basis<<<16, 256, 0, stream>>>(bases, basis, basisT);
  for (int st = 0; st < NUM_STAGES; ++st) {
    k_gemm1<<<dim3(64, 16), 256, 0, stream>>>(fT16, basisT, attn, attnT,
                                              st == NUM_STAGES - 1 ? 1 : 0);
    k_gemm2<<<dim3(16, nsl, 16), 256, 0, stream>>>(f16, attnT, brawT, slice_n);
    k_l2fused<<<dim3(16, 16), 256, 0, stream>>>(brawT, basisT, basis, nsl);
  }
  k_recon<<<dim3(64, 8, 16), 256, 0, stream>>>(attn, basis, out);
}

// Round 4
// 455.851 us; speedup vs baseline: 1.1802x; 1.0103x over previous
//
#include <hip/hip_runtime.h>
#include <stdint.h>

#define B_ 16
#define C_ 512
#define N_ 4096
#define K_ 64
#define NUM_STAGES 3

typedef __bf16 bf16x8 __attribute__((ext_vector_type(8)));
typedef float f32x4 __attribute__((ext_vector_type(4)));

__device__ __forceinline__ uint16_t f2bf(float x) {
  union { float f; uint32_t u; } v; v.f = x;
  uint32_t r = (v.u + 0x7FFFu + ((v.u >> 16) & 1u)) >> 16;
  return (uint16_t)r;
}

__device__ __forceinline__ void async16(const uint16_t* g, uint16_t* l) {
  __builtin_amdgcn_global_load_lds(
      (const __attribute__((address_space(1))) unsigned int*)g,
      (__attribute__((address_space(3))) unsigned int*)l, 16, 0, 0);
}

// ---------------- prep: fp32 feats -> bf16 f [B][C][N] and fT [B][N][C] ----
// (round-0 exact: 79us, 0 bank conflicts)
__global__ __launch_bounds__(256) void k_prep(const float* __restrict__ feats,
                                              uint16_t* __restrict__ f16,
                                              uint16_t* __restrict__ fT16) {
  __shared__ uint16_t tile[64][65];
  int b = blockIdx.z, c0 = blockIdx.y * 64, n0 = blockIdx.x * 64;
  int t = threadIdx.x;
  const float* src = feats + ((size_t)b * C_ + c0) * N_ + n0;
  uint16_t* dst = f16 + ((size_t)b * C_ + c0) * N_ + n0;
  int cl = t >> 4;          // 0..15
  int nl = (t & 15) * 4;    // 0..60
#pragma unroll
  for (int i = 0; i < 4; ++i) {
    int c = cl + 16 * i;
    float4 v = *(const float4*)(src + (size_t)c * N_ + nl);
    ushort4 x;
    x.x = f2bf(v.x); x.y = f2bf(v.y); x.z = f2bf(v.z); x.w = f2bf(v.w);
    *(ushort4*)(dst + (size_t)c * N_ + nl) = x;
    tile[c][nl + 0] = x.x; tile[c][nl + 1] = x.y;
    tile[c][nl + 2] = x.z; tile[c][nl + 3] = x.w;
  }
  __syncthreads();
  uint16_t* dstT = fT16 + ((size_t)b * N_ + n0) * C_ + c0;
#pragma unroll
  for (int i = 0; i < 4; ++i) {
    int n = cl + 16 * i;
    int c = nl;
    ushort4 y;
    y.x = tile[c + 0][n]; y.y = tile[c + 1][n];
    y.z = tile[c + 2][n]; y.w = tile[c + 3][n];
    *(ushort4*)(dstT + (size_t)n * C_ + c) = y;
  }
}

// ---------------- init: l2norm(bases over C) -> basis [B][C][K], basisT [B][K][C]
__global__ __launch_bounds__(256) void k_init_basis(const float* __restrict__ bases,
                                                    uint16_t* __restrict__ basis,
                                                    uint16_t* __restrict__ basisT) {
  int b = blockIdx.x;
  int t = threadIdx.x;
  __shared__ float red[256];
  __shared__ float inv[64];
  int k = t & 63;
  float s = 0.f;
  for (int c = (t >> 6); c < C_; c += 4) {
    float v = bases[c * K_ + k];
    s += v * v;
  }
  red[t] = s;
  __syncthreads();
  if (t < 64) {
    float tot = red[t] + red[t + 64] + red[t + 128] + red[t + 192];
    inv[t] = 1.f / (1e-6f + sqrtf(tot));
  }
  __syncthreads();
  uint16_t* ob = basis + (size_t)b * C_ * K_;
  for (int i = 0; i < (C_ * K_) / 256; ++i) {
    int idx = t + 256 * i;
    int kk = idx & 63;
    ob[idx] = f2bf(bases[idx] * inv[kk]);
  }
  uint16_t* obT = basisT + (size_t)b * K_ * C_;
  for (int i = 0; i < (C_ * K_) / 256; ++i) {
    int idx = t + 256 * i;
    int kk = idx >> 9;
    int cc = idx & 511;
    obT[idx] = f2bf(bases[cc * K_ + kk] * inv[kk]);
  }
}

// ---------------- GEMM1 + fused softmax, v5: BK=128 (half the barriers/drains)
// LDS 32 KB single-buffered; grid 1024 -> 4 blocks/CU unchanged.
__global__ __launch_bounds__(256) void k_gemm1(const uint16_t* __restrict__ fT,
                                               const uint16_t* __restrict__ basisT,
                                               uint16_t* __restrict__ attn,    // [B][N][K]
                                               uint16_t* __restrict__ attnT,   // [B][K][N]
                                               int write_attn) {
  __shared__ __attribute__((aligned(16))) uint16_t ldsA[64 * 128];  // 16 KB
  __shared__ __attribute__((aligned(16))) uint16_t ldsB[64 * 128];  // 16 KB
  int b = blockIdx.y;
  int n0 = blockIdx.x * 64;
  int t = threadIdx.x;
  int w = t >> 6, lane = t & 63, l15 = lane & 15, quad = lane >> 4;
  const uint16_t* A = fT + ((size_t)b * N_ + n0) * C_;
  const uint16_t* Bm = basisT + (size_t)b * K_ * C_;
  f32x4 acc[4] = {};
  for (int cs = 0; cs < C_; cs += 128) {
    __syncthreads();
    // stage 64 rows x 16 chunks (16B each), chunk-slot XOR-rotated by row
#pragma unroll
    for (int r = 0; r < 4; ++r) {
      int e = r * 256 + t;
      int row = e >> 4, ch = e & 15;
      int sch = (ch + row) & 15;
      async16(A + (size_t)row * C_ + cs + sch * 8, ldsA + (r * 256 + (t & 192)) * 8);
    }
#pragma unroll
    for (int r = 0; r < 4; ++r) {
      int e = r * 256 + t;
      int row = e >> 4, ch = e & 15;
      int sch = (ch + row) & 15;
      async16(Bm + (size_t)row * C_ + cs + sch * 8, ldsB + (r * 256 + (t & 192)) * 8);
    }
    __syncthreads();
#pragma unroll
    for (int s = 0; s < 4; ++s) {
      int cc = s * 4 + quad;               // chunk 0..15 within the 128-col tile
      int ra = 16 * w + l15;
      bf16x8 af = *(const bf16x8*)(ldsA + (ra * 16 + ((cc - ra) & 15)) * 8);
#pragma unroll
      for (int t4 = 0; t4 < 4; ++t4) {
        int rb = 16 * t4 + l15;
        bf16x8 bv = *(const bf16x8*)(ldsB + (rb * 16 + ((cc - rb) & 15)) * 8);
        acc[t4] = __builtin_amdgcn_mfma_f32_16x16x32_bf16(af, bv, acc[t4], 0, 0, 0);
      }
    }
  }
  float p[4][4];
#pragma unroll
  for (int r = 0; r < 4; ++r) {
    float m = fmaxf(fmaxf(acc[0][r], acc[1][r]), fmaxf(acc[2][r], acc[3][r]));
    m = fmaxf(m, __shfl_xor(m, 1));
    m = fmaxf(m, __shfl_xor(m, 2));
    m = fmaxf(m, __shfl_xor(m, 4));
    m = fmaxf(m, __shfl_xor(m, 8));
    float s = 0.f;
#pragma unroll
    for (int t4 = 0; t4 < 4; ++t4) { p[t4][r] = __expf(acc[t4][r] - m); s += p[t4][r]; }
    s += __shfl_xor(s, 1); s += __shfl_xor(s, 2);
    s += __shfl_xor(s, 4); s += __shfl_xor(s, 8);
    float inv = 1.f / s;
#pragma unroll
    for (int t4 = 0; t4 < 4; ++t4) p[t4][r] *= inv;
  }
  if (write_attn) {
    uint16_t* oa = attn + ((size_t)b * N_ + n0 + 16 * w + quad * 4) * K_;
#pragma unroll
    for (int r = 0; r < 4; ++r) {
#pragma unroll
      for (int t4 = 0; t4 < 4; ++t4) oa[(size_t)r * K_ + 16 * t4 + l15] = f2bf(p[t4][r]);
    }
  }
#pragma unroll
  for (int t4 = 0; t4 < 4; ++t4) {
    ushort4 y;
    y.x = f2bf(p[t4][0]); y.y = f2bf(p[t4][1]);
    y.z = f2bf(p[t4][2]); y.w = f2bf(p[t4][3]);
    *(ushort4*)(attnT + ((size_t)b * K_ + 16 * t4 + l15) * N_ + n0 + 16 * w + quad * 4) = y;
  }
}

// ---------------- GEMM2 v5: BK=128, split-K=4; LDS 24 KB
__global__ __launch_bounds__(256) void k_gemm2(const uint16_t* __restrict__ f16,
                                               const uint16_t* __restrict__ attnT,
                                               float* __restrict__ brawT,
                                               int slice_n) {
  __shared__ __attribute__((aligned(16))) uint16_t ldsA[32 * 128];  // 8 KB
  __shared__ __attribute__((aligned(16))) uint16_t ldsB[64 * 128];  // 16 KB
  int b = blockIdx.z;
  int c0 = blockIdx.x * 32;
  int slice = blockIdx.y;
  int ns0 = slice * slice_n;
  int t = threadIdx.x, w = t >> 6, lane = t & 63, l15 = lane & 15, quad = lane >> 4;
  int h = w >> 1, kh = w & 1;
  const uint16_t* A = f16 + ((size_t)b * C_ + c0) * N_;
  const uint16_t* Bm = attnT + (size_t)b * K_ * N_;
  f32x4 acc[2] = {};
  for (int ns = ns0; ns < ns0 + slice_n; ns += 128) {
    __syncthreads();
#pragma unroll
    for (int r = 0; r < 2; ++r) {
      int e = r * 256 + t;
      int row = e >> 4, ch = e & 15;
      int sch = (ch + row) & 15;
      async16(A + (size_t)row * N_ + ns + sch * 8, ldsA + (r * 256 + (t & 192)) * 8);
    }
#pragma unroll
    for (int r = 0; r < 4; ++r) {
      int e = r * 256 + t;
      int row = e >> 4, ch = e & 15;
      int sch = (ch + row) & 15;
      async16(Bm + (size_t)row * N_ + ns + sch * 8, ldsB + (r * 256 + (t & 192)) * 8);
    }
    __syncthreads();
#pragma unroll
    for (int s = 0; s < 4; ++s) {
      int cc = s * 4 + quad;
      int ra = 16 * h + l15;
      bf16x8 af = *(const bf16x8*)(ldsA + (ra * 16 + ((cc - ra) & 15)) * 8);
#pragma unroll
      for (int t2 = 0; t2 < 2; ++t2) {
        int rb = 32 * kh + 16 * t2 + l15;
        bf16x8 bv = *(const bf16x8*)(ldsB + (rb * 16 + ((cc - rb) & 15)) * 8);
        acc[t2] = __builtin_amdgcn_mfma_f32_16x16x32_bf16(af, bv, acc[t2], 0, 0, 0);
      }
    }
  }
  float* out = brawT + ((size_t)slice * B_ + b) * K_ * C_;
#pragma unroll
  for (int t2 = 0; t2 < 2; ++t2) {
    int k = 32 * kh + 16 * t2 + l15;
    float4 v = make_float4(acc[t2][0], acc[t2][1], acc[t2][2], acc[t2][3]);
    *(float4*)(out + (size_t)k * C_ + c0 + 16 * h + quad * 4) = v;
  }
}

// ---------------- FUSED l2norm + transpose: v5 wave-parallel reduction
__global__ __launch_bounds__(256) void k_l2fused(const float* __restrict__ brawT,
                                                 uint16_t* __restrict__ basisT,
                                                 uint16_t* __restrict__ basis,
                                                 int nsl) {
  __shared__ float red[4][128];
  __shared__ float invs[4];
  int b = blockIdx.x, kg = blockIdx.y;
  int t = threadIdx.x, lane = t & 63;
  int c4 = (t & 127) * 4;       // c chunk of 4
  int khalf = t >> 7;           // 0/1 -> k' = khalf*2 + i
  float4 bs[2];
  float pr[2];
#pragma unroll
  for (int i = 0; i < 2; ++i) {
    int k = kg * 4 + khalf * 2 + i;
    float4 a = make_float4(0.f, 0.f, 0.f, 0.f);
    for (int s = 0; s < nsl; ++s) {
      const float* rp = brawT + (((size_t)s * B_ + b) * K_ + k) * C_ + c4;
      float4 v = *(const float4*)rp;
      a.x += v.x; a.y += v.y; a.z += v.z; a.w += v.w;
    }
    bs[i] = a;
    pr[i] = a.x * a.x + a.y * a.y + a.z * a.z + a.w * a.w;
  }
  red[khalf * 2 + 0][t & 127] = pr[0];
  red[khalf * 2 + 1][t & 127] = pr[1];
  __syncthreads();
  {
    int g = t >> 6;   // wave g reduces k' = g
    float s = red[g][lane] + red[g][lane + 64];
    s += __shfl_xor(s, 1); s += __shfl_xor(s, 2); s += __shfl_xor(s, 4);
    s += __shfl_xor(s, 8); s += __shfl_xor(s, 16); s += __shfl_xor(s, 32);
    if (lane == 0) invs[g] = 1.f / (1e-6f + sqrtf(s));
  }
  __syncthreads();
#pragma unroll
  for (int i = 0; i < 2; ++i) {
    int kk = khalf * 2 + i;
    int k = kg * 4 + kk;
    float inv = invs[kk];
    ushort4 y;
    y.x = f2bf(bs[i].x * inv); y.y = f2bf(bs[i].y * inv);
    y.z = f2bf(bs[i].z * inv); y.w = f2bf(bs[i].w * inv);
    *(ushort4*)(basisT + ((size_t)b * K_ + k) * C_ + c4) = y;
    uint16_t* ob = basis + (size_t)b * C_ * K_ + k;
    ob[(size_t)(c4 + 0) * K_] = y.x;
    ob[(size_t)(c4 + 1) * K_] = y.y;
    ob[(size_t)(c4 + 2) * K_] = y.z;
    ob[(size_t)(c4 + 3) * K_] = y.w;
  }
}

// ---------------- recon: out[b,c,n] = sum_k basis[c,k]*attn[n,k] (fp32)
// round-0 tile; float4 epilogue (4 rows x 256B = 1KB per wave-instr)
__global__ __launch_bounds__(256) void k_recon(const uint16_t* __restrict__ attn,
                                               const uint16_t* __restrict__ basis,
                                               float* __restrict__ out) {
  __shared__ __attribute__((aligned(16))) char smem[64 * 68 * 4]; // 17.4 KB union
  uint16_t* ldsA = (uint16_t*)smem;              // 64 n x 64 k (8 KB)
  uint16_t* ldsB = (uint16_t*)(smem + 8192);     // 64 c x 64 k (8 KB)
  float* ldsT = (float*)smem;                    // 64 c x 68 n
  int b = blockIdx.z, c0 = blockIdx.y * 64, n0 = blockIdx.x * 64;
  int t = threadIdx.x, w = t >> 6, lane = t & 63, l15 = lane & 15, quad = lane >> 4;
  const uint16_t* A = attn + ((size_t)b * N_ + n0) * K_;
  const uint16_t* Bm = basis + ((size_t)b * C_ + c0) * K_;
#pragma unroll
  for (int r = 0; r < 2; ++r) {
    int e = r * 256 + t;
    int row = e >> 3, ch = e & 7, sch = (ch + row) & 7;
    async16(A + (size_t)row * K_ + sch * 8, ldsA + (r * 256 + (t & 192)) * 8);
  }
#pragma unroll
  for (int r = 0; r < 2; ++r) {
    int e = r * 256 + t;
    int row = e >> 3, ch = e & 7, sch = (ch + row) & 7;
    async16(Bm + (size_t)row * K_ + sch * 8, ldsB + (r * 256 + (t & 192)) * 8);
  }
  f32x4 acc[4] = {};
  __syncthreads();
#pragma unroll
  for (int s = 0; s < 2; ++s) {
    int cc = s * 4 + quad;
    int ra = 16 * w + l15;
    bf16x8 af = *(const bf16x8*)(ldsA + (ra * 8 + ((cc - ra) & 7)) * 8);
#pragma unroll
    for (int t4 = 0; t4 < 4; ++t4) {
      int rb = 16 * t4 + l15;
      bf16x8 bv = *(const bf16x8*)(ldsB + (rb * 8 + ((cc - rb) & 7)) * 8);
      acc[t4] = __builtin_amdgcn_mfma_f32_16x16x32_bf16(af, bv, acc[t4], 0, 0, 0);
    }
  }
  // transpose through LDS: acc holds D[n'][c'] with n'=16w+quad*4+r, c'=16t4+l15
  __syncthreads();
#pragma unroll
  for (int t4 = 0; t4 < 4; ++t4) {
    float4 v = make_float4(acc[t4][0], acc[t4][1], acc[t4][2], acc[t4][3]);
    *(float4*)(ldsT + (size_t)(16 * t4 + l15) * 68 + 16 * w + quad * 4) = v;
  }
  __syncthreads();
  float* op = out + ((size_t)b * C_ + c0) * N_ + n0;
  int n4 = l15 * 4;
#pragma unroll
  for (int j = 0; j < 4; ++j) {
    int c = 16 * j + 4 * w + quad;   // wave covers 4 rows x 256B = 1KB per instr
    *(float4*)(op + (size_t)c * N_ + n4) = *(const float4*)(ldsT + (size_t)c * 68 + n4);
  }
}

extern "C" void kernel_launch(void* const* d_in, const int* in_sizes, int n_in,
                              void* d_out, int out_size, void* d_ws, size_t ws_size,
                              hipStream_t stream) {
  const float* feats = (const float*)d_in[0];
  const float* bases = (const float*)d_in[1];
  float* out = (float*)d_out;
  char* ws = (char*)d_ws;
  uint16_t* f16 = (uint16_t*)(ws);                         // 64 MB
  uint16_t* fT16 = (uint16_t*)(ws + 67108864);             // 64 MB
  uint16_t* attn = (uint16_t*)(ws + 134217728);            // 8 MB
  uint16_t* attnT = (uint16_t*)(ws + 142606336);           // 8 MB
  uint16_t* basis = (uint16_t*)(ws + 150994944);           // 1 MB
  uint16_t* basisT = (uint16_t*)(ws + 152043520);          // 1 MB
  float* brawT = (float*)(ws + 153092096);                 // 8 MB (4 slices)

  const int nsl = 4;
  const int slice_n = N_ / nsl;   // 1024, divisible by BK=128

  k_prep<<<dim3(64, 8, 16), 256, 0, stream>>>(feats, f16, fT16);
  k_init_basis<<<16, 256, 0, stream>>>(bases, basis, basisT);
  for (int st = 0; st < NUM_STAGES; ++st) {
    k_gemm1<<<dim3(64, 16), 256, 0, stream>>>(fT16, basisT, attn, attnT,
                                              st == NUM_STAGES - 1 ? 1 : 0);
    k_gemm2<<<dim3(16, nsl, 16), 256, 0, stream>>>(f16, attnT, brawT, slice_n);
    k_l2fused<<<dim3(16, 16), 256, 0, stream>>>(brawT, basisT, basis, nsl);
  }
  k_recon<<<dim3(64, 8, 16), 256, 0, stream>>>(attn, basis, out);
}

// Round 5
// 445.491 us; speedup vs baseline: 1.2076x; 1.0233x over previous
//
#include <hip/hip_runtime.h>
#include <stdint.h>

#define B_ 16
#define C_ 512
#define N_ 4096
#define K_ 64
#define NUM_STAGES 3

typedef __bf16 bf16x8 __attribute__((ext_vector_type(8)));
typedef float f32x4 __attribute__((ext_vector_type(4)));

__device__ __forceinline__ uint16_t f2bf(float x) {
  union { float f; uint32_t u; } v; v.f = x;
  uint32_t r = (v.u + 0x7FFFu + ((v.u >> 16) & 1u)) >> 16;
  return (uint16_t)r;
}

__device__ __forceinline__ void async16(const uint16_t* g, uint16_t* l) {
  __builtin_amdgcn_global_load_lds(
      (const __attribute__((address_space(1))) unsigned int*)g,
      (__attribute__((address_space(3))) unsigned int*)l, 16, 0, 0);
}

// ---------------- prep v3: 128c x 128n tile, 256B store segments both outputs.
// LDS u32[128][64] with slot-XOR h(c)=2*((c>>3)&15): phase-1 b128 writes uniform,
// phase-2 b32 reads 2-way-broadcast (free). 16B ushort8 stores.
__global__ __launch_bounds__(256) void k_prep(const float* __restrict__ feats,
                                              uint16_t* __restrict__ f16,
                                              uint16_t* __restrict__ fT16) {
  __shared__ uint32_t tile[128][64];   // 32 KB
  int b = blockIdx.z, c0 = blockIdx.y * 128, n0 = blockIdx.x * 128;
  int t = threadIdx.x;
  int rl = t >> 4;          // 0..15
  int g = t & 15;           // 0..15
  const float* src = feats + ((size_t)b * C_ + c0) * N_ + n0;
  uint16_t* dst = f16 + ((size_t)b * C_ + c0) * N_ + n0;
#pragma unroll
  for (int i = 0; i < 8; ++i) {
    int c = rl + 16 * i;
    int n8 = g * 8;
    float4 v0 = *(const float4*)(src + (size_t)c * N_ + n8);
    float4 v1 = *(const float4*)(src + (size_t)c * N_ + n8 + 4);
    uint32_t q0 = (uint32_t)f2bf(v0.x) | ((uint32_t)f2bf(v0.y) << 16);
    uint32_t q1 = (uint32_t)f2bf(v0.z) | ((uint32_t)f2bf(v0.w) << 16);
    uint32_t q2 = (uint32_t)f2bf(v1.x) | ((uint32_t)f2bf(v1.y) << 16);
    uint32_t q3 = (uint32_t)f2bf(v1.z) | ((uint32_t)f2bf(v1.w) << 16);
    *(uint4*)(dst + (size_t)c * N_ + n8) = make_uint4(q0, q1, q2, q3);
    int h = 2 * ((c >> 3) & 15);
    int base = (4 * g) ^ (h & 28);
    int p = h & 3;   // 0 or 2: in-quad permutation
    uint32_t w[4];
    w[0 ^ p] = q0; w[1 ^ p] = q1; w[2 ^ p] = q2; w[3 ^ p] = q3;
    *(uint4*)&tile[c][base] = make_uint4(w[0], w[1], w[2], w[3]);
  }
  __syncthreads();
  uint16_t* dstT = fT16 + ((size_t)b * N_ + n0) * C_ + c0;
#pragma unroll
  for (int i = 0; i < 8; ++i) {
    int n = rl + 16 * i;
    int s = n >> 1, half = (n & 1) * 16;
    int c8 = g * 8;
    uint16_t e[8];
#pragma unroll
    for (int j = 0; j < 8; ++j) {
      int c = c8 + j;
      int h = 2 * ((c >> 3) & 15);
      uint32_t u = tile[c][s ^ h];
      e[j] = (uint16_t)(u >> half);
    }
    uint32_t q0 = (uint32_t)e[0] | ((uint32_t)e[1] << 16);
    uint32_t q1 = (uint32_t)e[2] | ((uint32_t)e[3] << 16);
    uint32_t q2 = (uint32_t)e[4] | ((uint32_t)e[5] << 16);
    uint32_t q3 = (uint32_t)e[6] | ((uint32_t)e[7] << 16);
    *(uint4*)(dstT + (size_t)n * C_ + c8) = make_uint4(q0, q1, q2, q3);
  }
}

// ---------------- init: l2norm(bases over C) -> basis [B][C][K], basisT [B][K][C]
__global__ __launch_bounds__(256) void k_init_basis(const float* __restrict__ bases,
                                                    uint16_t* __restrict__ basis,
                                                    uint16_t* __restrict__ basisT) {
  int b = blockIdx.x;
  int t = threadIdx.x;
  __shared__ float red[256];
  __shared__ float inv[64];
  int k = t & 63;
  float s = 0.f;
  for (int c = (t >> 6); c < C_; c += 4) {
    float v = bases[c * K_ + k];
    s += v * v;
  }
  red[t] = s;
  __syncthreads();
  if (t < 64) {
    float tot = red[t] + red[t + 64] + red[t + 128] + red[t + 192];
    inv[t] = 1.f / (1e-6f + sqrtf(tot));
  }
  __syncthreads();
  uint16_t* ob = basis + (size_t)b * C_ * K_;
  for (int i = 0; i < (C_ * K_) / 256; ++i) {
    int idx = t + 256 * i;
    int kk = idx & 63;
    ob[idx] = f2bf(bases[idx] * inv[kk]);
  }
  uint16_t* obT = basisT + (size_t)b * K_ * C_;
  for (int i = 0; i < (C_ * K_) / 256; ++i) {
    int idx = t + 256 * i;
    int kk = idx >> 9;
    int cc = idx & 511;
    obT[idx] = f2bf(bases[cc * K_ + kk] * inv[kk]);
  }
}

// ---------------- GEMM1 + fused softmax (round-0 exact config)
__global__ __launch_bounds__(256) void k_gemm1(const uint16_t* __restrict__ fT,
                                               const uint16_t* __restrict__ basisT,
                                               uint16_t* __restrict__ attn,    // [B][N][K]
                                               uint16_t* __restrict__ attnT,   // [B][K][N]
                                               int write_attn) {
  __shared__ __attribute__((aligned(16))) uint16_t ldsA[64 * 64];
  __shared__ __attribute__((aligned(16))) uint16_t ldsB[64 * 64];
  int b = blockIdx.y;
  int n0 = blockIdx.x * 64;
  int t = threadIdx.x;
  int w = t >> 6, lane = t & 63, l15 = lane & 15, quad = lane >> 4;
  const uint16_t* A = fT + ((size_t)b * N_ + n0) * C_;
  const uint16_t* Bm = basisT + (size_t)b * K_ * C_;
  f32x4 acc[4] = {};
  for (int cs = 0; cs < C_; cs += 64) {
    __syncthreads();
#pragma unroll
    for (int r = 0; r < 2; ++r) {
      int e = r * 256 + t;
      int row = e >> 3, ch = e & 7;
      int sch = (ch + row) & 7;
      async16(A + (size_t)row * C_ + cs + sch * 8, ldsA + (r * 256 + (t & 192)) * 8);
    }
#pragma unroll
    for (int r = 0; r < 2; ++r) {
      int e = r * 256 + t;
      int row = e >> 3, ch = e & 7;
      int sch = (ch + row) & 7;
      async16(Bm + (size_t)row * C_ + cs + sch * 8, ldsB + (r * 256 + (t & 192)) * 8);
    }
    __syncthreads();
#pragma unroll
    for (int s = 0; s < 2; ++s) {
      int cc = s * 4 + quad;
      int ra = 16 * w + l15;
      bf16x8 af = *(const bf16x8*)(ldsA + (ra * 8 + ((cc - ra) & 7)) * 8);
#pragma unroll
      for (int t4 = 0; t4 < 4; ++t4) {
        int rb = 16 * t4 + l15;
        bf16x8 bv = *(const bf16x8*)(ldsB + (rb * 8 + ((cc - rb) & 7)) * 8);
        acc[t4] = __builtin_amdgcn_mfma_f32_16x16x32_bf16(af, bv, acc[t4], 0, 0, 0);
      }
    }
  }
  float p[4][4];
#pragma unroll
  for (int r = 0; r < 4; ++r) {
    float m = fmaxf(fmaxf(acc[0][r], acc[1][r]), fmaxf(acc[2][r], acc[3][r]));
    m = fmaxf(m, __shfl_xor(m, 1));
    m = fmaxf(m, __shfl_xor(m, 2));
    m = fmaxf(m, __shfl_xor(m, 4));
    m = fmaxf(m, __shfl_xor(m, 8));
    float s = 0.f;
#pragma unroll
    for (int t4 = 0; t4 < 4; ++t4) { p[t4][r] = __expf(acc[t4][r] - m); s += p[t4][r]; }
    s += __shfl_xor(s, 1); s += __shfl_xor(s, 2);
    s += __shfl_xor(s, 4); s += __shfl_xor(s, 8);
    float inv = 1.f / s;
#pragma unroll
    for (int t4 = 0; t4 < 4; ++t4) p[t4][r] *= inv;
  }
  if (write_attn) {
    uint16_t* oa = attn + ((size_t)b * N_ + n0 + 16 * w + quad * 4) * K_;
#pragma unroll
    for (int r = 0; r < 4; ++r) {
#pragma unroll
      for (int t4 = 0; t4 < 4; ++t4) oa[(size_t)r * K_ + 16 * t4 + l15] = f2bf(p[t4][r]);
    }
  }
#pragma unroll
  for (int t4 = 0; t4 < 4; ++t4) {
    ushort4 y;
    y.x = f2bf(p[t4][0]); y.y = f2bf(p[t4][1]);
    y.z = f2bf(p[t4][2]); y.w = f2bf(p[t4][3]);
    *(ushort4*)(attnT + ((size_t)b * K_ + 16 * t4 + l15) * N_ + n0 + 16 * w + quad * 4) = y;
  }
}

// ---------------- GEMM2 (round-0 exact): brawT[s][b][k][c], split-K=4
__global__ __launch_bounds__(256) void k_gemm2(const uint16_t* __restrict__ f16,
                                               const uint16_t* __restrict__ attnT,
                                               float* __restrict__ brawT) {
  __shared__ __attribute__((aligned(16))) uint16_t ldsA[32 * 64];
  __shared__ __attribute__((aligned(16))) uint16_t ldsB[64 * 64];
  int b = blockIdx.z;
  int c0 = blockIdx.x * 32;
  int slice = blockIdx.y;
  int ns0 = slice * 1024;
  int t = threadIdx.x, w = t >> 6, lane = t & 63, l15 = lane & 15, quad = lane >> 4;
  int h = w >> 1, kh = w & 1;
  const uint16_t* A = f16 + ((size_t)b * C_ + c0) * N_;
  const uint16_t* Bm = attnT + (size_t)b * K_ * N_;
  f32x4 acc[2] = {};
  for (int ns = ns0; ns < ns0 + 1024; ns += 64) {
    __syncthreads();
    {
      int row = t >> 3, ch = t & 7;
      int sch = (ch + row) & 7;
      async16(A + (size_t)row * N_ + ns + sch * 8, ldsA + (t & 192) * 8);
    }
#pragma unroll
    for (int r = 0; r < 2; ++r) {
      int e = r * 256 + t;
      int row = e >> 3, ch = e & 7;
      int sch = (ch + row) & 7;
      async16(Bm + (size_t)row * N_ + ns + sch * 8, ldsB + (r * 256 + (t & 192)) * 8);
    }
    __syncthreads();
#pragma unroll
    for (int s = 0; s < 2; ++s) {
      int cc = s * 4 + quad;
      int ra = 16 * h + l15;
      bf16x8 af = *(const bf16x8*)(ldsA + (ra * 8 + ((cc - ra) & 7)) * 8);
#pragma unroll
      for (int t2 = 0; t2 < 2; ++t2) {
        int rb = 32 * kh + 16 * t2 + l15;
        bf16x8 bv = *(const bf16x8*)(ldsB + (rb * 8 + ((cc - rb) & 7)) * 8);
        acc[t2] = __builtin_amdgcn_mfma_f32_16x16x32_bf16(af, bv, acc[t2], 0, 0, 0);
      }
    }
  }
  float* out = brawT + ((size_t)slice * B_ + b) * K_ * C_;
#pragma unroll
  for (int t2 = 0; t2 < 2; ++t2) {
    int k = 32 * kh + 16 * t2 + l15;
    float4 v = make_float4(acc[t2][0], acc[t2][1], acc[t2][2], acc[t2][3]);
    *(float4*)(out + (size_t)k * C_ + c0 + 16 * h + quad * 4) = v;
  }
}

// ---------------- FUSED l2norm + transpose (wave-parallel reduction)
__global__ __launch_bounds__(256) void k_l2fused(const float* __restrict__ brawT,
                                                 uint16_t* __restrict__ basisT,
                                                 uint16_t* __restrict__ basis) {
  __shared__ float red[4][128];
  __shared__ float invs[4];
  int b = blockIdx.x, kg = blockIdx.y;
  int t = threadIdx.x, lane = t & 63;
  int c4 = (t & 127) * 4;       // c chunk of 4
  int khalf = t >> 7;           // 0/1 -> k' = khalf*2 + i
  float4 bs[2];
  float pr[2];
#pragma unroll
  for (int i = 0; i < 2; ++i) {
    int k = kg * 4 + khalf * 2 + i;
    float4 a = make_float4(0.f, 0.f, 0.f, 0.f);
#pragma unroll
    for (int s = 0; s < 4; ++s) {
      const float* rp = brawT + (((size_t)s * B_ + b) * K_ + k) * C_ + c4;
      float4 v = *(const float4*)rp;
      a.x += v.x; a.y += v.y; a.z += v.z; a.w += v.w;
    }
    bs[i] = a;
    pr[i] = a.x * a.x + a.y * a.y + a.z * a.z + a.w * a.w;
  }
  red[khalf * 2 + 0][t & 127] = pr[0];
  red[khalf * 2 + 1][t & 127] = pr[1];
  __syncthreads();
  {
    int g = t >> 6;   // wave g reduces k' = g
    float s = red[g][lane] + red[g][lane + 64];
    s += __shfl_xor(s, 1); s += __shfl_xor(s, 2); s += __shfl_xor(s, 4);
    s += __shfl_xor(s, 8); s += __shfl_xor(s, 16); s += __shfl_xor(s, 32);
    if (lane == 0) invs[g] = 1.f / (1e-6f + sqrtf(s));
  }
  __syncthreads();
#pragma unroll
  for (int i = 0; i < 2; ++i) {
    int kk = khalf * 2 + i;
    int k = kg * 4 + kk;
    float inv = invs[kk];
    ushort4 y;
    y.x = f2bf(bs[i].x * inv); y.y = f2bf(bs[i].y * inv);
    y.z = f2bf(bs[i].z * inv); y.w = f2bf(bs[i].w * inv);
    *(ushort4*)(basisT + ((size_t)b * K_ + k) * C_ + c4) = y;
    uint16_t* ob = basis + (size_t)b * C_ * K_ + k;
    ob[(size_t)(c4 + 0) * K_] = y.x;
    ob[(size_t)(c4 + 1) * K_] = y.y;
    ob[(size_t)(c4 + 2) * K_] = y.z;
    ob[(size_t)(c4 + 3) * K_] = y.w;
  }
}

// ---------------- recon: out[b,c,n] = sum_k basis[c,k]*attn[n,k] (fp32)
// round-0 tile; float4 epilogue (4 rows x 256B = 1KB per wave-instr)
__global__ __launch_bounds__(256) void k_recon(const uint16_t* __restrict__ attn,
                                               const uint16_t* __restrict__ basis,
                                               float* __restrict__ out) {
  __shared__ __attribute__((aligned(16))) char smem[64 * 68 * 4]; // 17.4 KB union
  uint16_t* ldsA = (uint16_t*)smem;              // 64 n x 64 k (8 KB)
  uint16_t* ldsB = (uint16_t*)(smem + 8192);     // 64 c x 64 k (8 KB)
  float* ldsT = (float*)smem;                    // 64 c x 68 n
  int b = blockIdx.z, c0 = blockIdx.y * 64, n0 = blockIdx.x * 64;
  int t = threadIdx.x, w = t >> 6, lane = t & 63, l15 = lane & 15, quad = lane >> 4;
  const uint16_t* A = attn + ((size_t)b * N_ + n0) * K_;
  const uint16_t* Bm = basis + ((size_t)b * C_ + c0) * K_;
#pragma unroll
  for (int r = 0; r < 2; ++r) {
    int e = r * 256 + t;
    int row = e >> 3, ch = e & 7, sch = (ch + row) & 7;
    async16(A + (size_t)row * K_ + sch * 8, ldsA + (r * 256 + (t & 192)) * 8);
  }
#pragma unroll
  for (int r = 0; r < 2; ++r) {
    int e = r * 256 + t;
    int row = e >> 3, ch = e & 7, sch = (ch + row) & 7;
    async16(Bm + (size_t)row * K_ + sch * 8, ldsB + (r * 256 + (t & 192)) * 8);
  }
  f32x4 acc[4] = {};
  __syncthreads();
#pragma unroll
  for (int s = 0; s < 2; ++s) {
    int cc = s * 4 + quad;
    int ra = 16 * w + l15;
    bf16x8 af = *(const bf16x8*)(ldsA + (ra * 8 + ((cc - ra) & 7)) * 8);
#pragma unroll
    for (int t4 = 0; t4 < 4; ++t4) {
      int rb = 16 * t4 + l15;
      bf16x8 bv = *(const bf16x8*)(ldsB + (rb * 8 + ((cc - rb) & 7)) * 8);
      acc[t4] = __builtin_amdgcn_mfma_f32_16x16x32_bf16(af, bv, acc[t4], 0, 0, 0);
    }
  }
  // transpose through LDS: acc holds D[n'][c'] with n'=16w+quad*4+r, c'=16t4+l15
  __syncthreads();
#pragma unroll
  for (int t4 = 0; t4 < 4; ++t4) {
    float4 v = make_float4(acc[t4][0], acc[t4][1], acc[t4][2], acc[t4][3]);
    *(float4*)(ldsT + (size_t)(16 * t4 + l15) * 68 + 16 * w + quad * 4) = v;
  }
  __syncthreads();
  float* op = out + ((size_t)b * C_ + c0) * N_ + n0;
  int n4 = l15 * 4;
#pragma unroll
  for (int j = 0; j < 4; ++j) {
    int c = 16 * j + 4 * w + quad;   // wave covers 4 rows x 256B = 1KB per instr
    *(float4*)(op + (size_t)c * N_ + n4) = *(const float4*)(ldsT + (size_t)c * 68 + n4);
  }
}

extern "C" void kernel_launch(void* const* d_in, const int* in_sizes, int n_in,
                              void* d_out, int out_size, void* d_ws, size_t ws_size,
                              hipStream_t stream) {
  const float* feats = (const float*)d_in[0];
  const float* bases = (const float*)d_in[1];
  float* out = (float*)d_out;
  char* ws = (char*)d_ws;
  uint16_t* f16 = (uint16_t*)(ws);                         // 64 MB
  uint16_t* fT16 = (uint16_t*)(ws + 67108864);             // 64 MB
  uint16_t* attn = (uint16_t*)(ws + 134217728);            // 8 MB
  uint16_t* attnT = (uint16_t*)(ws + 142606336);           // 8 MB
  uint16_t* basis = (uint16_t*)(ws + 150994944);           // 1 MB
  uint16_t* basisT = (uint16_t*)(ws + 152043520);          // 1 MB
  float* brawT = (float*)(ws + 153092096);                 // 8 MB (4 slices)

  k_prep<<<dim3(32, 4, 16), 256, 0, stream>>>(feats, f16, fT16);
  k_init_basis<<<16, 256, 0, stream>>>(bases, basis, basisT);
  for (int st = 0; st < NUM_STAGES; ++st) {
    k_gemm1<<<dim3(64, 16), 256, 0, stream>>>(fT16, basisT, attn, attnT,
                                              st == NUM_STAGES - 1 ? 1 : 0);
    k_gemm2<<<dim3(16, 4, 16), 256, 0, stream>>>(f16, attnT, brawT);
    k_l2fused<<<dim3(16, 16), 256, 0, stream>>>(brawT, basisT, basis);
  }
  k_recon<<<dim3(64, 8, 16), 256, 0, stream>>>(attn, basis, out);
}

// Round 8
// 443.533 us; speedup vs baseline: 1.2129x; 1.0044x over previous
//
#include <hip/hip_runtime.h>
#include <stdint.h>

#define B_ 16
#define C_ 512
#define N_ 4096
#define K_ 64
#define NUM_STAGES 3

typedef __bf16 bf16x8 __attribute__((ext_vector_type(8)));
typedef float f32x4 __attribute__((ext_vector_type(4)));
typedef uint32_t u32x2 __attribute__((ext_vector_type(2)));

__device__ __forceinline__ uint16_t f2bf(float x) {
  union { float f; uint32_t u; } v; v.f = x;
  uint32_t r = (v.u + 0x7FFFu + ((v.u >> 16) & 1u)) >> 16;
  return (uint16_t)r;
}

__device__ __forceinline__ void async16(const uint16_t* g, uint16_t* l) {
  __builtin_amdgcn_global_load_lds(
      (const __attribute__((address_space(1))) unsigned int*)g,
      (__attribute__((address_space(3))) unsigned int*)l, 16, 0, 0);
}

// ---------------- prep v4: pure streaming fp32 -> bf16 convert (f16 only).
// No LDS, no barriers. 134MB R + 67MB W.
__global__ __launch_bounds__(256) void k_prep(const float* __restrict__ feats,
                                              uint16_t* __restrict__ f16) {
  const size_t total = (size_t)B_ * C_ * N_;
  size_t i = ((size_t)blockIdx.x * 256 + threadIdx.x) * 8;
  const size_t stride = (size_t)gridDim.x * 256 * 8;
  for (; i < total; i += stride) {
    float4 v0 = *(const float4*)(feats + i);
    float4 v1 = *(const float4*)(feats + i + 4);
    uint32_t q0 = (uint32_t)f2bf(v0.x) | ((uint32_t)f2bf(v0.y) << 16);
    uint32_t q1 = (uint32_t)f2bf(v0.z) | ((uint32_t)f2bf(v0.w) << 16);
    uint32_t q2 = (uint32_t)f2bf(v1.x) | ((uint32_t)f2bf(v1.y) << 16);
    uint32_t q3 = (uint32_t)f2bf(v1.z) | ((uint32_t)f2bf(v1.w) << 16);
    *(uint4*)(f16 + i) = make_uint4(q0, q1, q2, q3);
  }
}

// ---------------- init: l2norm(bases over C) -> basis [B][C][K], basisT [B][K][C]
__global__ __launch_bounds__(256) void k_init_basis(const float* __restrict__ bases,
                                                    uint16_t* __restrict__ basis,
                                                    uint16_t* __restrict__ basisT) {
  int b = blockIdx.x;
  int t = threadIdx.x;
  __shared__ float red[256];
  __shared__ float inv[64];
  int k = t & 63;
  float s = 0.f;
  for (int c = (t >> 6); c < C_; c += 4) {
    float v = bases[c * K_ + k];
    s += v * v;
  }
  red[t] = s;
  __syncthreads();
  if (t < 64) {
    float tot = red[t] + red[t + 64] + red[t + 128] + red[t + 192];
    inv[t] = 1.f / (1e-6f + sqrtf(tot));
  }
  __syncthreads();
  uint16_t* ob = basis + (size_t)b * C_ * K_;
  for (int i = 0; i < (C_ * K_) / 256; ++i) {
    int idx = t + 256 * i;
    int kk = idx & 63;
    ob[idx] = f2bf(bases[idx] * inv[kk]);
  }
  uint16_t* obT = basisT + (size_t)b * K_ * C_;
  for (int i = 0; i < (C_ * K_) / 256; ++i) {
    int idx = t + 256 * i;
    int kk = idx >> 9;
    int cc = idx & 511;
    obT[idx] = f2bf(bases[cc * K_ + kk] * inv[kk]);
  }
}

// ---------------- GEMM1 v6b: A read from f16[c][n] (no fT).
// A staged into [4c][16n]-subtiled LDS (linear dest, permuted global src);
// A-fragments via ds_read_b64_tr_b16 (HW transpose).
// Semantics (m156/m162): each lane contributes its OWN 64b at its addr to the
// 16-lane group's 128B window; HW redistributes so lane l gets column l&15 of
// the 4x16 row-major bf16 tile. => per-lane addr = groupbase + (l&15)*8B,
// groupbase = w*2048 + quad*128 (i.e. addr = base + lane*8).
// Subtile position p holds c-block sc(p) = (p&8) + 2*(p&3) + ((p>>2)&1):
// offsets 0/512/1024/1536B -> lane-group q reads c = 8q / 8q+4 / 32+8q / 32+8q+4.
__global__ __launch_bounds__(256) void k_gemm1(const uint16_t* __restrict__ f16,
                                               const uint16_t* __restrict__ basisT,
                                               uint16_t* __restrict__ attn,    // [B][N][K]
                                               uint16_t* __restrict__ attnT,   // [B][K][N]
                                               int write_attn) {
  __shared__ __attribute__((aligned(16))) uint16_t ldsA[64 * 64];  // 8 KB subtiled
  __shared__ __attribute__((aligned(16))) uint16_t ldsB[64 * 64];  // 8 KB round-0
  int b = blockIdx.y;
  int n0 = blockIdx.x * 64;
  int t = threadIdx.x;
  int w = t >> 6, lane = t & 63, l15 = lane & 15, quad = lane >> 4;
  const uint16_t* A = f16 + (size_t)b * C_ * N_;           // [c][n]
  const uint16_t* Bm = basisT + (size_t)b * K_ * C_;
  // staging source (c,n) for slots o = t and o = t+256:
  // o: ng=o>>7 (wave-region), p=(o>>3)&15 (subtile pos), e=o&7 (slot in subtile)
  // -> c = 4*sc(p)+(e>>1), n = n0 + 16*ng + 8*(e&1)
  int cA[2], nA[2];
#pragma unroll
  for (int r = 0; r < 2; ++r) {
    int o = r * 256 + t;
    int ng = o >> 7, p = (o >> 3) & 15, e = o & 7;
    int sc = (p & 8) + ((p & 3) << 1) + ((p >> 2) & 1);
    cA[r] = 4 * sc + (e >> 1);
    nA[r] = n0 + 16 * ng + 8 * (e & 1);
  }
  uint32_t aBase =
      (uint32_t)(uintptr_t)(const __attribute__((address_space(3))) uint16_t*)ldsA;
  uint32_t trAddr = aBase + (uint32_t)w * 2048u + (uint32_t)lane * 8u;
  f32x4 acc[4] = {};
  for (int cs = 0; cs < C_; cs += 64) {
    __syncthreads();
#pragma unroll
    for (int r = 0; r < 2; ++r) {
      async16(A + (size_t)(cs + cA[r]) * N_ + nA[r],
              ldsA + (r * 256 + (t & 192)) * 8);
    }
#pragma unroll
    for (int r = 0; r < 2; ++r) {
      int e = r * 256 + t;
      int row = e >> 3, ch = e & 7;
      int sch = (ch + row) & 7;
      async16(Bm + (size_t)row * C_ + cs + sch * 8, ldsB + (r * 256 + (t & 192)) * 8);
    }
    __syncthreads();
    u32x2 q0, q1, q2, q3;
    asm volatile("ds_read_b64_tr_b16 %0, %1" : "=v"(q0) : "v"(trAddr));
    asm volatile("ds_read_b64_tr_b16 %0, %1 offset:512" : "=v"(q1) : "v"(trAddr));
    asm volatile("ds_read_b64_tr_b16 %0, %1 offset:1024" : "=v"(q2) : "v"(trAddr));
    asm volatile("ds_read_b64_tr_b16 %0, %1 offset:1536" : "=v"(q3) : "v"(trAddr));
    asm volatile("s_waitcnt lgkmcnt(0)" ::: "memory");
    __builtin_amdgcn_sched_barrier(0);
    bf16x8 af0, af1;
    ((u32x2*)&af0)[0] = q0; ((u32x2*)&af0)[1] = q1;
    ((u32x2*)&af1)[0] = q2; ((u32x2*)&af1)[1] = q3;
#pragma unroll
    for (int s = 0; s < 2; ++s) {
      int cc = s * 4 + quad;
      bf16x8 af = s ? af1 : af0;
#pragma unroll
      for (int t4 = 0; t4 < 4; ++t4) {
        int rb = 16 * t4 + l15;
        bf16x8 bv = *(const bf16x8*)(ldsB + (rb * 8 + ((cc - rb) & 7)) * 8);
        acc[t4] = __builtin_amdgcn_mfma_f32_16x16x32_bf16(af, bv, acc[t4], 0, 0, 0);
      }
    }
  }
  float p[4][4];
#pragma unroll
  for (int r = 0; r < 4; ++r) {
    float m = fmaxf(fmaxf(acc[0][r], acc[1][r]), fmaxf(acc[2][r], acc[3][r]));
    m = fmaxf(m, __shfl_xor(m, 1));
    m = fmaxf(m, __shfl_xor(m, 2));
    m = fmaxf(m, __shfl_xor(m, 4));
    m = fmaxf(m, __shfl_xor(m, 8));
    float s = 0.f;
#pragma unroll
    for (int t4 = 0; t4 < 4; ++t4) { p[t4][r] = __expf(acc[t4][r] - m); s += p[t4][r]; }
    s += __shfl_xor(s, 1); s += __shfl_xor(s, 2);
    s += __shfl_xor(s, 4); s += __shfl_xor(s, 8);
    float inv = 1.f / s;
#pragma unroll
    for (int t4 = 0; t4 < 4; ++t4) p[t4][r] *= inv;
  }
  if (write_attn) {
    uint16_t* oa = attn + ((size_t)b * N_ + n0 + 16 * w + quad * 4) * K_;
#pragma unroll
    for (int r = 0; r < 4; ++r) {
#pragma unroll
      for (int t4 = 0; t4 < 4; ++t4) oa[(size_t)r * K_ + 16 * t4 + l15] = f2bf(p[t4][r]);
    }
  }
#pragma unroll
  for (int t4 = 0; t4 < 4; ++t4) {
    ushort4 y;
    y.x = f2bf(p[t4][0]); y.y = f2bf(p[t4][1]);
    y.z = f2bf(p[t4][2]); y.w = f2bf(p[t4][3]);
    *(ushort4*)(attnT + ((size_t)b * K_ + 16 * t4 + l15) * N_ + n0 + 16 * w + quad * 4) = y;
  }
}

// ---------------- GEMM2 (round-0 exact): brawT[s][b][k][c], split-K=4
__global__ __launch_bounds__(256) void k_gemm2(const uint16_t* __restrict__ f16,
                                               const uint16_t* __restrict__ attnT,
                                               float* __restrict__ brawT) {
  __shared__ __attribute__((aligned(16))) uint16_t ldsA[32 * 64];
  __shared__ __attribute__((aligned(16))) uint16_t ldsB[64 * 64];
  int b = blockIdx.z;
  int c0 = blockIdx.x * 32;
  int slice = blockIdx.y;
  int ns0 = slice * 1024;
  int t = threadIdx.x, w = t >> 6, lane = t & 63, l15 = lane & 15, quad = lane >> 4;
  int h = w >> 1, kh = w & 1;
  const uint16_t* A = f16 + ((size_t)b * C_ + c0) * N_;
  const uint16_t* Bm = attnT + (size_t)b * K_ * N_;
  f32x4 acc[2] = {};
  for (int ns = ns0; ns < ns0 + 1024; ns += 64) {
    __syncthreads();
    {
      int row = t >> 3, ch = t & 7;
      int sch = (ch + row) & 7;
      async16(A + (size_t)row * N_ + ns + sch * 8, ldsA + (t & 192) * 8);
    }
#pragma unroll
    for (int r = 0; r < 2; ++r) {
      int e = r * 256 + t;
      int row = e >> 3, ch = e & 7;
      int sch = (ch + row) & 7;
      async16(Bm + (size_t)row * N_ + ns + sch * 8, ldsB + (r * 256 + (t & 192)) * 8);
    }
    __syncthreads();
#pragma unroll
    for (int s = 0; s < 2; ++s) {
      int cc = s * 4 + quad;
      int ra = 16 * h + l15;
      bf16x8 af = *(const bf16x8*)(ldsA + (ra * 8 + ((cc - ra) & 7)) * 8);
#pragma unroll
      for (int t2 = 0; t2 < 2; ++t2) {
        int rb = 32 * kh + 16 * t2 + l15;
        bf16x8 bv = *(const bf16x8*)(ldsB + (rb * 8 + ((cc - rb) & 7)) * 8);
        acc[t2] = __builtin_amdgcn_mfma_f32_16x16x32_bf16(af, bv, acc[t2], 0, 0, 0);
      }
    }
  }
  float* out = brawT + ((size_t)slice * B_ + b) * K_ * C_;
#pragma unroll
  for (int t2 = 0; t2 < 2; ++t2) {
    int k = 32 * kh + 16 * t2 + l15;
    float4 v = make_float4(acc[t2][0], acc[t2][1], acc[t2][2], acc[t2][3]);
    *(float4*)(out + (size_t)k * C_ + c0 + 16 * h + quad * 4) = v;
  }
}

// ---------------- FUSED l2norm + transpose (wave-parallel reduction)
__global__ __launch_bounds__(256) void k_l2fused(const float* __restrict__ brawT,
                                                 uint16_t* __restrict__ basisT,
                                                 uint16_t* __restrict__ basis) {
  __shared__ float red[4][128];
  __shared__ float invs[4];
  int b = blockIdx.x, kg = blockIdx.y;
  int t = threadIdx.x, lane = t & 63;
  int c4 = (t & 127) * 4;       // c chunk of 4
  int khalf = t >> 7;           // 0/1 -> k' = khalf*2 + i
  float4 bs[2];
  float pr[2];
#pragma unroll
  for (int i = 0; i < 2; ++i) {
    int k = kg * 4 + khalf * 2 + i;
    float4 a = make_float4(0.f, 0.f, 0.f, 0.f);
#pragma unroll
    for (int s = 0; s < 4; ++s) {
      const float* rp = brawT + (((size_t)s * B_ + b) * K_ + k) * C_ + c4;
      float4 v = *(const float4*)rp;
      a.x += v.x; a.y += v.y; a.z += v.z; a.w += v.w;
    }
    bs[i] = a;
    pr[i] = a.x * a.x + a.y * a.y + a.z * a.z + a.w * a.w;
  }
  red[khalf * 2 + 0][t & 127] = pr[0];
  red[khalf * 2 + 1][t & 127] = pr[1];
  __syncthreads();
  {
    int g = t >> 6;   // wave g reduces k' = g
    float s = red[g][lane] + red[g][lane + 64];
    s += __shfl_xor(s, 1); s += __shfl_xor(s, 2); s += __shfl_xor(s, 4);
    s += __shfl_xor(s, 8); s += __shfl_xor(s, 16); s += __shfl_xor(s, 32);
    if (lane == 0) invs[g] = 1.f / (1e-6f + sqrtf(s));
  }
  __syncthreads();
#pragma unroll
  for (int i = 0; i < 2; ++i) {
    int kk = khalf * 2 + i;
    int k = kg * 4 + kk;
    float inv = invs[kk];
    ushort4 y;
    y.x = f2bf(bs[i].x * inv); y.y = f2bf(bs[i].y * inv);
    y.z = f2bf(bs[i].z * inv); y.w = f2bf(bs[i].w * inv);
    *(ushort4*)(basisT + ((size_t)b * K_ + k) * C_ + c4) = y;
    uint16_t* ob = basis + (size_t)b * C_ * K_ + k;
    ob[(size_t)(c4 + 0) * K_] = y.x;
    ob[(size_t)(c4 + 1) * K_] = y.y;
    ob[(size_t)(c4 + 2) * K_] = y.z;
    ob[(size_t)(c4 + 3) * K_] = y.w;
  }
}

// ---------------- recon: out[b,c,n] = sum_k basis[c,k]*attn[n,k] (fp32)
// round-0 tile; float4 epilogue (4 rows x 256B = 1KB per wave-instr)
__global__ __launch_bounds__(256) void k_recon(const uint16_t* __restrict__ attn,
                                               const uint16_t* __restrict__ basis,
                                               float* __restrict__ out) {
  __shared__ __attribute__((aligned(16))) char smem[64 * 68 * 4]; // 17.4 KB union
  uint16_t* ldsA = (uint16_t*)smem;              // 64 n x 64 k (8 KB)
  uint16_t* ldsB = (uint16_t*)(smem + 8192);     // 64 c x 64 k (8 KB)
  float* ldsT = (float*)smem;                    // 64 c x 68 n
  int b = blockIdx.z, c0 = blockIdx.y * 64, n0 = blockIdx.x * 64;
  int t = threadIdx.x, w = t >> 6, lane = t & 63, l15 = lane & 15, quad = lane >> 4;
  const uint16_t* A = attn + ((size_t)b * N_ + n0) * K_;
  const uint16_t* Bm = basis + ((size_t)b * C_ + c0) * K_;
#pragma unroll
  for (int r = 0; r < 2; ++r) {
    int e = r * 256 + t;
    int row = e >> 3, ch = e & 7, sch = (ch + row) & 7;
    async16(A + (size_t)row * K_ + sch * 8, ldsA + (r * 256 + (t & 192)) * 8);
  }
#pragma unroll
  for (int r = 0; r < 2; ++r) {
    int e = r * 256 + t;
    int row = e >> 3, ch = e & 7, sch = (ch + row) & 7;
    async16(Bm + (size_t)row * K_ + sch * 8, ldsB + (r * 256 + (t & 192)) * 8);
  }
  f32x4 acc[4] = {};
  __syncthreads();
#pragma unroll
  for (int s = 0; s < 2; ++s) {
    int cc = s * 4 + quad;
    int ra = 16 * w + l15;
    bf16x8 af = *(const bf16x8*)(ldsA + (ra * 8 + ((cc - ra) & 7)) * 8);
#pragma unroll
    for (int t4 = 0; t4 < 4; ++t4) {
      int rb = 16 * t4 + l15;
      bf16x8 bv = *(const bf16x8*)(ldsB + (rb * 8 + ((cc - rb) & 7)) * 8);
      acc[t4] = __builtin_amdgcn_mfma_f32_16x16x32_bf16(af, bv, acc[t4], 0, 0, 0);
    }
  }
  // transpose through LDS: acc holds D[n'][c'] with n'=16w+quad*4+r, c'=16t4+l15
  __syncthreads();
#pragma unroll
  for (int t4 = 0; t4 < 4; ++t4) {
    float4 v = make_float4(acc[t4][0], acc[t4][1], acc[t4][2], acc[t4][3]);
    *(float4*)(ldsT + (size_t)(16 * t4 + l15) * 68 + 16 * w + quad * 4) = v;
  }
  __syncthreads();
  float* op = out + ((size_t)b * C_ + c0) * N_ + n0;
  int n4 = l15 * 4;
#pragma unroll
  for (int j = 0; j < 4; ++j) {
    int c = 16 * j + 4 * w + quad;   // wave covers 4 rows x 256B = 1KB per instr
    *(float4*)(op + (size_t)c * N_ + n4) = *(const float4*)(ldsT + (size_t)c * 68 + n4);
  }
}

extern "C" void kernel_launch(void* const* d_in, const int* in_sizes, int n_in,
                              void* d_out, int out_size, void* d_ws, size_t ws_size,
                              hipStream_t stream) {
  const float* feats = (const float*)d_in[0];
  const float* bases = (const float*)d_in[1];
  float* out = (float*)d_out;
  char* ws = (char*)d_ws;
  uint16_t* f16 = (uint16_t*)(ws);                         // 64 MB
  uint16_t* attn = (uint16_t*)(ws + 67108864);             // 8 MB
  uint16_t* attnT = (uint16_t*)(ws + 75497472);            // 8 MB
  uint16_t* basis = (uint16_t*)(ws + 83886080);            // 1 MB
  uint16_t* basisT = (uint16_t*)(ws + 84934656);           // 1 MB
  float* brawT = (float*)(ws + 85983232);                  // 8 MB (4 slices)

  k_prep<<<2048, 256, 0, stream>>>(feats, f16);
  k_init_basis<<<16, 256, 0, stream>>>(bases, basis, basisT);
  for (int st = 0; st < NUM_STAGES; ++st) {
    k_gemm1<<<dim3(64, 16), 256, 0, stream>>>(f16, basisT, attn, attnT,
                                              st == NUM_STAGES - 1 ? 1 : 0);
    k_gemm2<<<dim3(16, 4, 16), 256, 0, stream>>>(f16, attnT, brawT);
    k_l2fused<<<dim3(16, 16), 256, 0, stream>>>(brawT, basisT, basis);
  }
  k_recon<<<dim3(64, 8, 16), 256, 0, stream>>>(attn, basis, out);
}